// Round 1
// baseline (843.118 us; speedup 1.0000x reference)
//
#include <hip/hip_runtime.h>
#include <math.h>

// ---------------------------------------------------------------------------
// voting / segment-mean / argmax kernel set
// shapes (fixed dataset): B=512, T=50, N=6400, L=10
// ws layout: seg_sum A[L*N] | counts int[L]
// ---------------------------------------------------------------------------

template <typename A>
__global__ void zero_ws_k(A* __restrict__ seg, int* __restrict__ counts,
                          int segN, int L) {
    int i = blockIdx.x * blockDim.x + threadIdx.x;
    if (i < segN) seg[i] = (A)0;
    if (i < L) counts[i] = 0;
}

__global__ void count_k(const int* __restrict__ labels, int* __restrict__ counts,
                        int B) {
    int b = blockIdx.x * blockDim.x + threadIdx.x;
    if (b < B) atomicAdd(&counts[labels[b]], 1);
}

// Hot kernel: one thread = one float4 column (4 n's) for one batch sample b.
// Coalesced: 64 lanes x 16B = 1KB contiguous per wave per t-step.
template <typename A>
__global__ void accum4_k(const float* __restrict__ spikes,
                         const int* __restrict__ labels,
                         A* __restrict__ seg, int T, int N) {
    const int b = blockIdx.y;
    const int v = blockIdx.x * blockDim.x + threadIdx.x;  // float4 index
    const int V = N >> 2;
    if (v >= V) return;
    const float4* p = (const float4*)(spikes + (size_t)b * T * N) + v;
    A s0 = 0, s1 = 0, s2 = 0, s3 = 0;
#pragma unroll 5
    for (int t = 0; t < T; ++t) {
        float4 x = p[(size_t)t * V];
        s0 += (A)x.x; s1 += (A)x.y; s2 += (A)x.z; s3 += (A)x.w;
    }
    const int l = labels[b];  // wave-uniform -> scalar load
    A* dst = seg + (size_t)l * N + (size_t)v * 4;
    atomicAdd(dst + 0, s0);
    atomicAdd(dst + 1, s1);
    atomicAdd(dst + 2, s2);
    atomicAdd(dst + 3, s3);
}

// Scalar fallback when N % 4 != 0 (not expected for this dataset).
template <typename A>
__global__ void accum1_k(const float* __restrict__ spikes,
                         const int* __restrict__ labels,
                         A* __restrict__ seg, int T, int N) {
    const int b = blockIdx.y;
    const int n = blockIdx.x * blockDim.x + threadIdx.x;
    if (n >= N) return;
    const float* p = spikes + (size_t)b * T * N + n;
    A s = 0;
    for (int t = 0; t < T; ++t) s += (A)p[(size_t)t * N];
    atomicAdd(seg + (size_t)labels[b] * N + n, s);
}

template <typename A>
__global__ void finalize_k(const A* __restrict__ seg, const int* __restrict__ counts,
                           const float* __restrict__ rates, float* __restrict__ out,
                           int N, int L, float alpha) {
    int n = blockIdx.x * blockDim.x + threadIdx.x;
    if (n >= N) return;
    float best = -INFINITY;
    int bi = 0;
    for (int l = 0; l < L; ++l) {
        float r = rates[(size_t)n * L + l];
        int c = counts[l];
        // mean = seg / max(c,1); update only where c > 0 (ALPHA = 1.0)
        float v = (c > 0) ? (alpha * r + (float)(seg[(size_t)l * N + n] / (A)c)) : r;
        out[(size_t)N + (size_t)n * L + l] = v;
        if (v > best) { best = v; bi = l; }  // strict > => first max (jnp.argmax)
    }
    out[n] = (float)bi;
}

template <typename A>
static void run_path(const float* spikes, const int* labels, const float* rates,
                     float* out, void* d_ws, int B, int T, int N, int L,
                     hipStream_t stream) {
    const int segN = L * N;
    A* seg = (A*)d_ws;
    int* counts = (int*)((char*)d_ws + (size_t)segN * sizeof(A));

    int zthreads = 256;
    int zblocks = (segN + zthreads - 1) / zthreads;  // segN >> L, covers counts too
    zero_ws_k<A><<<dim3(zblocks), dim3(zthreads), 0, stream>>>(seg, counts, segN, L);

    count_k<<<dim3((B + 255) / 256), dim3(256), 0, stream>>>(labels, counts, B);

    if ((N & 3) == 0) {
        const int V = N >> 2;
        const int th = 320;  // 5 waves; 6400/4 = 1600 = 5 * 320 exactly
        dim3 g((V + th - 1) / th, B);
        accum4_k<A><<<g, dim3(th), 0, stream>>>(spikes, labels, seg, T, N);
    } else {
        dim3 g((N + 255) / 256, B);
        accum1_k<A><<<g, dim3(256), 0, stream>>>(spikes, labels, seg, T, N);
    }

    finalize_k<A><<<dim3((N + 255) / 256), dim3(256), 0, stream>>>(
        seg, counts, rates, out, N, L, 1.0f);
}

extern "C" void kernel_launch(void* const* d_in, const int* in_sizes, int n_in,
                              void* d_out, int out_size, void* d_ws, size_t ws_size,
                              hipStream_t stream) {
    const float* spikes = (const float*)d_in[0];
    const int*   labels = (const int*)d_in[1];
    const float* rates  = (const float*)d_in[2];
    // d_in[3] is n_labels (device scalar); L fixed at 10 for this dataset.
    const int L = 10;
    const int B = in_sizes[1];
    const int N = in_sizes[2] / L;
    const int T = in_sizes[0] / (B * N);
    float* out = (float*)d_out;

    const size_t needD = (size_t)L * N * sizeof(double) + 64;
    if (ws_size >= needD) {
        run_path<double>(spikes, labels, rates, out, d_ws, B, T, N, L, stream);
    } else {
        run_path<float>(spikes, labels, rates, out, d_ws, B, T, N, L, stream);
    }
}